// Round 7
// baseline (1394.517 us; speedup 1.0000x reference)
//
#include <hip/hip_runtime.h>
#include <stdint.h>

typedef unsigned short u16;
typedef __attribute__((ext_vector_type(8))) short bf16x8;
typedef __attribute__((ext_vector_type(4))) float f32x4;

#define HD 256
#define KX 320   // extended K: 64 (padded features) + 256

static __device__ __forceinline__ float b2f(u16 x){
  union{float f; unsigned u;} v; v.u = ((unsigned)x)<<16; return v.f;
}
static __device__ __forceinline__ u16 f2b(float f){
  union{float f; unsigned u;} v; v.f = f;
  unsigned r = v.u + 0x7fffu + ((v.u>>16)&1u);
  return (u16)(r>>16);
}
static __device__ __forceinline__ void acc4(float* a, uint2 v){
  a[0] += b2f((u16)v.x); a[1] += b2f((u16)(v.x>>16));
  a[2] += b2f((u16)v.y); a[3] += b2f((u16)(v.y>>16));
}

// ---------------- zero int buffer ----------------
__global__ void k_zero_int(int* __restrict__ p, int n){
  int i = blockIdx.x*256 + threadIdx.x;
  if (i < n) p[i] = 0;
}

// ---------------- histogram ----------------
__global__ void k_hist(const int* __restrict__ key, int* __restrict__ deg, int n){
  int i = blockIdx.x*256 + threadIdx.x;
  if (i < n) atomicAdd(&deg[key[i]], 1);
}

// ---------------- single-block exclusive scan ----------------
__global__ __launch_bounds__(1024) void k_scan(const int* __restrict__ deg, int* __restrict__ start,
                                               int* __restrict__ cursor, int n){
  __shared__ int sm[1024];
  const int t = threadIdx.x;
  const int chunk = (n + 1023) >> 10;
  const int lo = t*chunk, hi = min(lo+chunk, n);
  int s = 0;
  for (int i=lo;i<hi;i++) s += deg[i];
  sm[t] = s;
  __syncthreads();
  for (int ofs=1; ofs<1024; ofs<<=1){
    int v = (t>=ofs) ? sm[t-ofs] : 0;
    __syncthreads();
    sm[t] += v;
    __syncthreads();
  }
  int base = sm[t] - s;
  for (int i=lo;i<hi;i++){
    start[i] = base; cursor[i] = base;
    base += deg[i];
  }
  if (t == 1023) start[n] = sm[1023];
}

// ---------------- fill buckets ----------------
__global__ void k_fill(const int* __restrict__ key, const int* __restrict__ val,
                       int* __restrict__ cursor, int* __restrict__ bucket, int n){
  int i = blockIdx.x*256 + threadIdx.x;
  if (i >= n) return;
  int pos = atomicAdd(&cursor[key[i]], 1);
  bucket[pos] = val ? val[i] : i;
}

// ---------------- alpha16[v] = bf16( sum_{j} tree_m[bucket[j]] ) ----------------
__global__ void k_alpha_gather(const float* __restrict__ tree_m, const int* __restrict__ start,
                               const int* __restrict__ bucket, u16* __restrict__ alpha16, int N){
  int v = (int)(((long long)blockIdx.x*blockDim.x + threadIdx.x)>>6);
  int l = threadIdx.x & 63;
  if (v >= N) return;
  int s = start[v], e2 = start[v+1];
  float a0=0.f,a1=0.f,a2=0.f,a3=0.f;
  for (int j=s;j<e2;j++){
    float4 tv = *(const float4*)(tree_m + (long long)bucket[j]*HD + l*4);
    a0 += tv.x; a1 += tv.y; a2 += tv.z; a3 += tv.w;
  }
  ushort4 o; o.x=f2b(a0); o.y=f2b(a1); o.z=f2b(a2); o.w=f2b(a3);
  *(ushort4*)(alpha16 + (long long)v*HD + l*4) = o;
}

// ---------------- frag-major B prep ----------------
// BTf[(ks*16+nj)*512 + l*8 + i] = W[k][n], n = nj*16+(l&15), k = ks*32+(l>>4)*8+i.
__global__ void k_prep_B(const float* __restrict__ Wi, const float* __restrict__ Wh,
                         const float* __restrict__ Wo,
                         u16* __restrict__ BTf_bp, u16* __restrict__ BTf_fo){
  int g = blockIdx.x*256 + threadIdx.x;   // 81920 total
  if (g >= 81920) return;
  int i = g & 7;
  int l = (g>>3) & 63;
  int t = g >> 9;                // 0..159
  int nj = t & 15, ks = t >> 4;  // ks 0..9
  int n = nj*16 + (l & 15);
  int k = ks*32 + (l>>4)*8 + i;
  float bp = 0.f, fo = 0.f;
  if (k < 40) bp = Wi[k*HD + n];
  else if (k >= 64) bp = Wh[(k-64)*HD + n];
  if (k < 35) fo = Wo[k*HD + n];
  else if (k >= 64) fo = Wo[(k-29)*HD + n];
  BTf_bp[g] = f2b(bp);
  BTf_fo[g] = f2b(fo);
}

// ---------------- segment pointers over sorted lg_dst ----------------
__global__ void k_segptr(const int* __restrict__ lg_dst, int L, int E, int* __restrict__ start){
  int e = blockIdx.x*256 + threadIdx.x;
  if (e > E) return;
  int lo = 0, hi = L;
  while (lo < hi){ int mid = (lo+hi)>>1; if (lg_dst[mid] < e) lo = mid+1; else hi = mid; }
  start[e] = lo;
}

// ---------------- fused MPNN GEMM, wave-per-16-rows, 32 KB LDS -> 5 blocks/CU ----------------
// Features (k<64) load straight into A-frags per lane; gather region staged in a
// wave-private 16x256 u16 LDS slice (exactly 32768 B/block).
// mode 0: A=[x_src|xe|0], ksteps 2; mode 1: +lg_gather+alpha_src, ksteps 10 (out16)
// mode 2: A=[x_node|0|dst_gather+alpha_row], ksteps 10 (out32, +bias)
__global__ __launch_bounds__(256, 5) void k_mpnn(
    const float* __restrict__ xn, const float* __restrict__ xe,
    const u16* __restrict__ msg_in, const u16* __restrict__ alpha16,
    const int* __restrict__ seg, const int* __restrict__ keys,
    const int* __restrict__ esrc,
    const u16* __restrict__ BTf, const float* __restrict__ bias,
    u16* __restrict__ out16, float* __restrict__ out32, int M, int Lkeys, int mode)
{
  __shared__ u16 G_lds[4][16][256];   // 32,768 B
  const int tid = threadIdx.x;
  const int wave = tid>>6, l = tid&63;
  const int lr = l&15, lq = l>>4;
  const int m0 = blockIdx.x*64 + wave*16;
  u16* Gw = &G_lds[wave][0][0];

  // per-lane row metadata (lane l's A-row is lr; __shfl(x, r) reads lane r's row-r data)
  const int rowl = m0 + lr;
  const bool rvl = rowl < M;
  int srcl = 0, sl = 0, el = 0;
  if (rvl){
    srcl = (mode==2) ? rowl : esrc[rowl];
    if (mode != 0){ sl = seg[rowl]; el = seg[rowl+1]; }
  }

  bf16x8 af[10];
  // ---- A frags ks0,1: raw features straight to registers (fragment layout)
  #pragma unroll
  for (int ks=0; ks<2; ks++){
    #pragma unroll
    for (int i=0;i<8;i++){
      int k = ks*32 + lq*8 + i;
      float v = 0.f;
      if (rvl){
        if (k < 35) v = xn[(long long)srcl*35 + k];
        else if (k < 40 && mode != 2) v = xe[(long long)rowl*5 + (k-35)];
      }
      af[ks][i] = (short)f2b(v);
    }
  }

  // ---- gather region -> LDS: coalesced 512-B msg-row loads, keys via shuffle broadcast
  if (mode != 0){
    const int base = __shfl(sl, 0);
    int kc0 = (base + l      < Lkeys) ? keys[base + l]      : 0;
    int kc1 = (base + 64 + l < Lkeys) ? keys[base + 64 + l] : 0;
    auto keyat = [&](int j)->int{
      int idx = j - base;
      if (idx < 64)  return __shfl(kc0, idx);
      if (idx < 128) return __shfl(kc1, idx-64);
      return keys[j];
    };
    const u16* msg_l = msg_in + l*4;
    for (int r=0; r<16; r++){
      int s  = __shfl(sl, r);
      int e  = __shfl(el, r);
      int an = __shfl(srcl, r);
      float a[4];
      { uint2 av = *(const uint2*)(alpha16 + (long long)an*HD + l*4);
        a[0]=b2f((u16)av.x); a[1]=b2f((u16)(av.x>>16));
        a[2]=b2f((u16)av.y); a[3]=b2f((u16)(av.y>>16)); }
      int j = s;
      for (; j+4 <= e; j+=4){
        int q0 = keyat(j), q1 = keyat(j+1), q2 = keyat(j+2), q3 = keyat(j+3);
        uint2 v0 = *(const uint2*)(msg_l + (long long)q0*HD);
        uint2 v1 = *(const uint2*)(msg_l + (long long)q1*HD);
        uint2 v2 = *(const uint2*)(msg_l + (long long)q2*HD);
        uint2 v3 = *(const uint2*)(msg_l + (long long)q3*HD);
        acc4(a, v0); acc4(a, v1); acc4(a, v2); acc4(a, v3);
      }
      for (; j < e; j++){
        int q = keyat(j);
        uint2 v = *(const uint2*)(msg_l + (long long)q*HD);
        acc4(a, v);
      }
      ushort4 o; o.x=f2b(a[0]); o.y=f2b(a[1]); o.z=f2b(a[2]); o.w=f2b(a[3]);
      *(ushort4*)&Gw[r*256 + l*4] = o;
    }
    // ---- A-frags ks2..9 from wave-private LDS (no barrier needed)
    const u16* Gr = &G_lds[wave][lr][0];
    #pragma unroll
    for (int ks=2; ks<10; ks++) af[ks] = *(const bf16x8*)(Gr + (ks-2)*32 + lq*8);
  }

  // ---- MFMA: frag-major B, fully coalesced loads
  f32x4 acc[16];
  #pragma unroll
  for (int nj=0;nj<16;nj++) acc[nj] = (f32x4){0.f,0.f,0.f,0.f};
  const u16* bb = BTf + l*8;

#define KSTEP(ks) { \
    _Pragma("unroll") \
    for (int nj=0;nj<16;nj++){ \
      bf16x8 bf = *(const bf16x8*)(bb + ((ks)*16+nj)*512); \
      acc[nj] = __builtin_amdgcn_mfma_f32_16x16x32_bf16(af[ks], bf, acc[nj], 0,0,0); \
    } }
  KSTEP(0) KSTEP(1)
  if (mode != 0){
    KSTEP(2) KSTEP(3) KSTEP(4) KSTEP(5)
    KSTEP(6) KSTEP(7) KSTEP(8) KSTEP(9)
  }
#undef KSTEP

  // ---- epilogue: C/D layout col=lr, row=lq*4+reg
  #pragma unroll
  for (int reg=0; reg<4; reg++){
    int gm = m0 + lq*4 + reg;
    if (gm < M){
      if (mode == 2){
        #pragma unroll
        for (int nj=0;nj<16;nj++){
          int col = nj*16 + lr;
          float v = acc[nj][reg] + bias[col];
          out32[(long long)gm*HD + col] = v > 0.f ? v : 0.f;
        }
      } else {
        #pragma unroll
        for (int nj=0;nj<16;nj++){
          int col = nj*16 + lr;
          float v = acc[nj][reg];
          out16[(long long)gm*HD + col] = f2b(v > 0.f ? v : 0.f);
        }
      }
    }
  }
}

// ---------------- graph mean (graph_ids sorted), fp32 in/out ----------------
__global__ void k_graph_mean(const float* __restrict__ h, const int* __restrict__ gid,
                             int N, int G, float* __restrict__ out){
  int g = (int)(((long long)blockIdx.x*blockDim.x + threadIdx.x)>>6);
  int l = threadIdx.x & 63;
  if (g >= G) return;
  int lo=0, hi=N;
  while (lo<hi){ int mid=(lo+hi)>>1; if (gid[mid] < g) lo=mid+1; else hi=mid; }
  int b = lo;
  hi = N;
  while (lo<hi){ int mid=(lo+hi)>>1; if (gid[mid] < g+1) lo=mid+1; else hi=mid; }
  int e2 = lo;
  float a0=0.f,a1=0.f,a2=0.f,a3=0.f;
  for (int v=b; v<e2; v++){
    float4 hv = *(const float4*)(h + (long long)v*HD + l*4);
    a0 += hv.x; a1 += hv.y; a2 += hv.z; a3 += hv.w;
  }
  int cnt = e2 - b; if (cnt < 1) cnt = 1;
  float inv = 1.0f/(float)cnt;
  float4 o; o.x=a0*inv; o.y=a1*inv; o.z=a2*inv; o.w=a3*inv;
  *(float4*)(out + (long long)g*HD + l*4) = o;
}

extern "C" void kernel_launch(void* const* d_in, const int* in_sizes, int n_in,
                              void* d_out, int out_size, void* d_ws, size_t ws_size,
                              hipStream_t stream){
  const float* x_nodes = (const float*)d_in[0];
  const float* x_edges = (const float*)d_in[1];
  const float* tree_m  = (const float*)d_in[2];
  const float* W_i     = (const float*)d_in[3];
  const float* W_h     = (const float*)d_in[4];
  const float* W_o     = (const float*)d_in[5];
  const float* b_o     = (const float*)d_in[6];
  const int* edge_src = (const int*)d_in[7];
  const int* edge_dst = (const int*)d_in[8];
  const int* lg_src   = (const int*)d_in[9];
  const int* lg_dst   = (const int*)d_in[10];
  const int* tgt      = (const int*)d_in[11];
  const int* teid     = (const int*)d_in[12];
  const int* gid      = (const int*)d_in[13];

  const int N = in_sizes[0]/35;
  const int E = in_sizes[1]/5;
  const int L = in_sizes[9];
  const int K = in_sizes[11];
  const int G = out_size/HD;

  // ---- workspace layout (~231.5 MB footprint, proven safe) ----
  char* wsb = (char*)d_ws;
  auto align256 = [](size_t x){ return (x + 255) & ~(size_t)255; };
  size_t oMsgA    = 0;
  size_t oMsgB    = oMsgA    + align256((size_t)E*HD*2);   // 102.4 MB
  size_t oAlpha16 = oMsgB    + align256((size_t)E*HD*2);   // 102.4 MB
  size_t oBTbp    = oAlpha16 + align256((size_t)N*HD*2);   // 25.6 MB
  size_t oBTfo    = oBTbp    + align256((size_t)81920*2);  // 160 KB
  size_t oStart   = oBTfo    + align256((size_t)81920*2);  // 160 KB

  u16*   msgA    = (u16*)(wsb + oMsgA);
  u16*   msgB    = (u16*)(wsb + oMsgB);
  u16*   alpha16 = (u16*)(wsb + oAlpha16);
  u16*   BTf_bp  = (u16*)(wsb + oBTbp);
  u16*   BTf_fo  = (u16*)(wsb + oBTfo);
  int*   startp  = (int*)(wsb + oStart);

  // tgt-CSR: in msgB region, consumed before BP iter1 writes msgB
  const size_t SLOT = 262144;
  int* deg_t    = (int*)(wsb + oMsgB + 0*SLOT);
  int* start_t  = (int*)(wsb + oMsgB + 1*SLOT);
  int* cursor_t = (int*)(wsb + oMsgB + 2*SLOT);
  int* bucket_t = (int*)(wsb + oMsgB + 3*SLOT);

  // dst-CSR + hbuf: in msgA region, used only after BP iter3 (msgA dead)
  float* hbuf   = (float*)(wsb + oMsgA);                   // 51.2 MB
  size_t oCsrD  = oMsgA + align256((size_t)N*HD*4) + 4096;
  int* deg_d    = (int*)(wsb + oCsrD + 0*SLOT);
  int* start_d  = (int*)(wsb + oCsrD + 1*SLOT);
  int* cursor_d = (int*)(wsb + oCsrD + 2*SLOT);
  int* bucket_d = (int*)(wsb + oCsrD + 3*SLOT);

  const int ngrid = (N+255)/256;
  const int egrid256 = (E+255)/256;
  const int kgrid256 = (K+255)/256;

  k_prep_B<<<320, 256, 0, stream>>>(W_i, W_h, W_o, BTf_bp, BTf_fo);
  k_segptr<<<(E+1+255)/256, 256, 0, stream>>>(lg_dst, L, E, startp);

  // tgt-CSR + alpha gather
  k_zero_int<<<ngrid, 256, 0, stream>>>(deg_t, N);
  k_hist<<<kgrid256, 256, 0, stream>>>(tgt, deg_t, K);
  k_scan<<<1, 1024, 0, stream>>>(deg_t, start_t, cursor_t, N);
  k_fill<<<kgrid256, 256, 0, stream>>>(tgt, teid, cursor_t, bucket_t, K);
  k_alpha_gather<<<(N+3)/4, 256, 0, stream>>>(tree_m, start_t, bucket_t, alpha16, N);

  const int egrid = (E+63)/64;
  // iter0: msgA = relu([x_src|xe] @ Wi)
  k_mpnn<<<egrid, 256, 0, stream>>>(x_nodes, x_edges, (const u16*)0, alpha16,
                                    startp, lg_src, edge_src, BTf_bp, (const float*)0,
                                    msgA, (float*)0, E, 0, 0);
  // BP iters: A -> B -> A -> B
  k_mpnn<<<egrid, 256, 0, stream>>>(x_nodes, x_edges, msgA, alpha16,
                                    startp, lg_src, edge_src, BTf_bp, (const float*)0,
                                    msgB, (float*)0, E, L, 1);
  k_mpnn<<<egrid, 256, 0, stream>>>(x_nodes, x_edges, msgB, alpha16,
                                    startp, lg_src, edge_src, BTf_bp, (const float*)0,
                                    msgA, (float*)0, E, L, 1);
  k_mpnn<<<egrid, 256, 0, stream>>>(x_nodes, x_edges, msgA, alpha16,
                                    startp, lg_src, edge_src, BTf_bp, (const float*)0,
                                    msgB, (float*)0, E, L, 1);
  // dst-CSR (msgA dead; final msg in msgB)
  k_zero_int<<<ngrid, 256, 0, stream>>>(deg_d, N);
  k_hist<<<egrid256, 256, 0, stream>>>(edge_dst, deg_d, E);
  k_scan<<<1, 1024, 0, stream>>>(deg_d, start_d, cursor_d, N);
  k_fill<<<egrid256, 256, 0, stream>>>(edge_dst, (const int*)0, cursor_d, bucket_d, E);
  // output layer with fused m-gather
  k_mpnn<<<(N+63)/64, 256, 0, stream>>>(x_nodes, (const float*)0, msgB, alpha16,
                                        start_d, bucket_d, (const int*)0, BTf_fo, b_o,
                                        (u16*)0, hbuf, N, E, 2);
  k_graph_mean<<<(G+3)/4, 256, 0, stream>>>(hbuf, gid, N, G, (float*)d_out);
}